// Round 6
// baseline (269.337 us; speedup 1.0000x reference)
//
#include <hip/hip_runtime.h>
#include <hip/hip_fp16.h>
#include <stdint.h>

#define BB 512
#define TT 1024
#define II 15
#define HH 64
#define OO 11

typedef __fp16 half2v __attribute__((ext_vector_type(2)));
typedef _Float16 half8 __attribute__((ext_vector_type(8)));
typedef float floatx4 __attribute__((ext_vector_type(4)));
typedef int int4v __attribute__((ext_vector_type(4)));

union PK { int i; half2v h; float f; };

__device__ __forceinline__ half2v i2h2(int v) { PK u; u.i = v; return u.h; }
__device__ __forceinline__ int h22i(half2v v) { PK u; u.h = v; return u.i; }

__device__ __forceinline__ float FDOT2(half2v a, half2v b, float c) {
    return __builtin_amdgcn_fdot2(a, b, c, false);
}

__device__ __forceinline__ float lane_xor1(float v) {
    PK u; u.f = v;
    // quad_perm(1,0,3,2) = 0xB1 : lane -> lane^1
    u.i = __builtin_amdgcn_mov_dpp(u.i, 0xB1, 0xF, 0xF, false);
    return u.f;
}

__device__ __forceinline__ float lane_xor2(float v) {
    PK u; u.f = v;
    // quad_perm(2,3,0,1) = 0x4E : lane -> lane^2
    u.i = __builtin_amdgcn_mov_dpp(u.i, 0x4E, 0xF, 0xF, false);
    return u.f;
}

// Drain LDS ops, then workgroup barrier (safe in wave-uniform branches;
// every wave executes exactly TT/64 = 16 of these).
__device__ __forceinline__ void block_sync() {
    asm volatile("s_waitcnt lgkmcnt(0)" ::: "memory");
    __builtin_amdgcn_s_barrier();
}

// v8: R5's wave-specialized structure (rec waves 0-1 alone on their SIMDs,
// decode consumers on waves 2-3, hring + 1 barrier/chunk) with the rec
// W_hh matvec moved OFF the VALU onto the MATRIX pipe.
//   A (row-replicated h): all 16 rows of A = h(t-1), so the m-mapping is
//     don't-care; lane l needs h[8*(l>>4)+j] / h[32+8*(l>>4)+j] — exactly two
//     lane-addressed ds_read_b128 from the hring slot (4 unique addrs each =
//     free LDS broadcast). Replaces 6 uniform b128 + 8 readlane + hpk pack.
//   B (W_hh resident): 4 n-groups x 2 K-halves, bf[g][s] lane l =
//     W_hh[16g+(l&15)][32s+8*(l>>4)+j] (32 VGPRs, replaces whh[32]).
//   8 independent mfma_f32_16x16x32_f16 (C=0), 4 adds merge K-halves,
//   3 cndmask select group l>>4, + xproj sum, relu, cvt, ring write.
// All three fragment layouts are confirmed by the previously-passing
// rnn_decode kernel (same builtin, same mappings). Deletes ~110 cyc of VALU
// issue (32 dot2 + readlanes + tree) from the 450-cyc serial step.
__global__ __launch_bounds__(256) void rnn_fused(
    const float* __restrict__ x, const float* __restrict__ W_ih,
    const float* __restrict__ b_ih, const float* __restrict__ W_hh,
    const float* __restrict__ b_hh, const float* __restrict__ W_dec,
    const float* __restrict__ b_dec, float* __restrict__ out,
    float* __restrict__ h_last)
{
    __shared__ __align__(16) int xbuf[2][2][64 * 8];        // 8 KiB
    __shared__ __align__(16) _Float16 hring[2][128][HH];    // 32 KiB
    const int tid  = threadIdx.x;
    const int lane = tid & 63;
    const int wid  = tid >> 6;

    if (wid < 2) {
        // ---------------- recurrence producer (MFMA body) ----------------
        const int w = wid;
        const int b = blockIdx.x * 2 + w;

        // W_hh B-fragments: bf[g][s][j] = W_hh[16g+(lane&15)][32s+8*(lane>>4)+j]
        const int nl = lane & 15;
        const int kq = lane >> 4;
        half8 bf[4][2];
#pragma unroll
        for (int g = 0; g < 4; ++g)
#pragma unroll
            for (int s = 0; s < 2; ++s)
#pragma unroll
                for (int j = 0; j < 8; ++j)
                    bf[g][s][j] = (_Float16)W_hh[(16 * g + nl) * HH +
                                                 32 * s + 8 * kq + j];

        // input weights; pair 7 = (w14, bias) matching x pair (x14, 1.0)
        half2v wx[8];
#pragma unroll
        for (int j = 0; j < 7; ++j)
            wx[j] = __builtin_amdgcn_cvt_pkrtz(W_ih[lane * II + 2 * j],
                                               W_ih[lane * II + 2 * j + 1]);
        wx[7] = __builtin_amdgcn_cvt_pkrtz(W_ih[lane * II + 14],
                                           b_ih[lane] + b_hh[lane]);

        const float* xb = x + (size_t)b * TT * II;

        // stage chunk 0 into xbuf[w][0]: lane ts packs x[b][ts][0..14] -> 8 pairs
        {
            float cf[II];
#pragma unroll
            for (int i = 0; i < II; ++i) cf[i] = xb[lane * II + i];
            int4v p0, p1;
            p0.x = h22i(__builtin_amdgcn_cvt_pkrtz(cf[0], cf[1]));
            p0.y = h22i(__builtin_amdgcn_cvt_pkrtz(cf[2], cf[3]));
            p0.z = h22i(__builtin_amdgcn_cvt_pkrtz(cf[4], cf[5]));
            p0.w = h22i(__builtin_amdgcn_cvt_pkrtz(cf[6], cf[7]));
            p1.x = h22i(__builtin_amdgcn_cvt_pkrtz(cf[8], cf[9]));
            p1.y = h22i(__builtin_amdgcn_cvt_pkrtz(cf[10], cf[11]));
            p1.z = h22i(__builtin_amdgcn_cvt_pkrtz(cf[12], cf[13]));
            p1.w = h22i(__builtin_amdgcn_cvt_pkrtz(cf[14], 1.0f));
            *(int4v*)&xbuf[w][0][lane * 8] = p0;
            *(int4v*)&xbuf[w][0][lane * 8 + 4] = p1;
        }
        hring[w][127][lane] = (_Float16)0.0f;    // h(-1) = 0 lives in slot 127

        // xproj accumulators for step 0 (read back slot 0; wave-synchronous)
        float xa[8];
        {
            const int4v xv0 = *(const int4v*)&xbuf[w][0][0];
            const int4v xv1 = *(const int4v*)&xbuf[w][0][4];
            xa[0] = FDOT2(i2h2(xv0.x), wx[0], 0.0f);
            xa[1] = FDOT2(i2h2(xv0.y), wx[1], 0.0f);
            xa[2] = FDOT2(i2h2(xv0.z), wx[2], 0.0f);
            xa[3] = FDOT2(i2h2(xv0.w), wx[3], 0.0f);
            xa[4] = FDOT2(i2h2(xv1.x), wx[4], 0.0f);
            xa[5] = FDOT2(i2h2(xv1.y), wx[5], 0.0f);
            xa[6] = FDOT2(i2h2(xv1.z), wx[6], 0.0f);
            xa[7] = FDOT2(i2h2(xv1.w), wx[7], 0.0f);
        }

        float h = 0.0f;
        const int aoff = kq * 16;               // A-frag byte offset in row
        const bool b4 = (lane & 16) != 0;       // group-select bits
        const bool b5 = (lane & 32) != 0;
        const floatx4 zc = {0.0f, 0.0f, 0.0f, 0.0f};

        auto step = [&](int t) {
            // A-fragments of h(t-1) straight from ring slot (t-1)&127:
            // lane l reads h[8*(l>>4)..+7] and h[32+8*(l>>4)..+7]
            const char* hrow = (const char*)&hring[w][(t + 127) & 127][0];
            const half8 a0 = *(const half8*)(hrow + aoff);
            const half8 a1 = *(const half8*)(hrow + 64 + aoff);

            // xproj total for THIS step (fills the A-read latency window)
            const float xs = ((xa[0] + xa[1]) + (xa[2] + xa[3])) +
                             ((xa[4] + xa[5]) + (xa[6] + xa[7]));

            // x pairs for step t+1 (DS reads queued behind the A reads)
            const int tn = t + 1;
            const int* xp = &xbuf[w][(tn >> 6) & 1][(tn & 63) * 8];
            const int4v xv0 = *(const int4v*)xp;
            const int4v xv1 = *(const int4v*)(xp + 4);

            // 8 independent MFMAs on the matrix pipe: group g covers outputs
            // 16g..16g+15; K-halves summed on the VALU (breaks mfma chaining)
            floatx4 c0 = __builtin_amdgcn_mfma_f32_16x16x32_f16(a0, bf[0][0], zc, 0, 0, 0);
            floatx4 d0 = __builtin_amdgcn_mfma_f32_16x16x32_f16(a1, bf[0][1], zc, 0, 0, 0);
            floatx4 c1 = __builtin_amdgcn_mfma_f32_16x16x32_f16(a0, bf[1][0], zc, 0, 0, 0);
            floatx4 d1 = __builtin_amdgcn_mfma_f32_16x16x32_f16(a1, bf[1][1], zc, 0, 0, 0);
            floatx4 c2 = __builtin_amdgcn_mfma_f32_16x16x32_f16(a0, bf[2][0], zc, 0, 0, 0);
            floatx4 d2 = __builtin_amdgcn_mfma_f32_16x16x32_f16(a1, bf[2][1], zc, 0, 0, 0);
            floatx4 c3 = __builtin_amdgcn_mfma_f32_16x16x32_f16(a0, bf[3][0], zc, 0, 0, 0);
            floatx4 d3 = __builtin_amdgcn_mfma_f32_16x16x32_f16(a1, bf[3][1], zc, 0, 0, 0);

            const float v0 = c0[0] + d0[0];     // rows replicated; row 0 is fine
            const float v1 = c1[0] + d1[0];
            const float v2 = c2[0] + d2[0];
            const float v3 = c3[0] + d3[0];
            const float r01 = b4 ? v1 : v0;     // lane picks its group l>>4
            const float r23 = b4 ? v3 : v2;
            const float hpre = b5 ? r23 : r01;

            h = fmaxf(hpre + xs, 0.0f);
            hring[w][t & 127][lane] = (_Float16)h;   // publish h(t) to ring

            // xproj partials for t+1 (consumes xv late; off the chain)
            xa[0] = FDOT2(i2h2(xv0.x), wx[0], 0.0f);
            xa[1] = FDOT2(i2h2(xv0.y), wx[1], 0.0f);
            xa[2] = FDOT2(i2h2(xv0.z), wx[2], 0.0f);
            xa[3] = FDOT2(i2h2(xv0.w), wx[3], 0.0f);
            xa[4] = FDOT2(i2h2(xv1.x), wx[4], 0.0f);
            xa[5] = FDOT2(i2h2(xv1.y), wx[5], 0.0f);
            xa[6] = FDOT2(i2h2(xv1.z), wx[6], 0.0f);
            xa[7] = FDOT2(i2h2(xv1.w), wx[7], 0.0f);
        };

        for (int tc = 0; tc < TT; tc += 64) {
            // global prefetch of the next chunk (re-reads current on last one)
            const int tnb = (tc + 64 < TT) ? (tc + 64) : tc;
            float nf[II];
#pragma unroll
            for (int i = 0; i < II; ++i)
                nf[i] = xb[(size_t)(tnb + lane) * II + i];

            for (int to = 0; to < 32; to += 8)
#pragma unroll
                for (int u = 0; u < 8; ++u) step(tc + to + u);

            // commit prefetched chunk into the other xbuf half
            {
                const int cb = ((tc >> 6) + 1) & 1;
                int4v p0, p1;
                p0.x = h22i(__builtin_amdgcn_cvt_pkrtz(nf[0], nf[1]));
                p0.y = h22i(__builtin_amdgcn_cvt_pkrtz(nf[2], nf[3]));
                p0.z = h22i(__builtin_amdgcn_cvt_pkrtz(nf[4], nf[5]));
                p0.w = h22i(__builtin_amdgcn_cvt_pkrtz(nf[6], nf[7]));
                p1.x = h22i(__builtin_amdgcn_cvt_pkrtz(nf[8], nf[9]));
                p1.y = h22i(__builtin_amdgcn_cvt_pkrtz(nf[10], nf[11]));
                p1.z = h22i(__builtin_amdgcn_cvt_pkrtz(nf[12], nf[13]));
                p1.w = h22i(__builtin_amdgcn_cvt_pkrtz(nf[14], 1.0f));
                *(int4v*)&xbuf[w][cb][lane * 8] = p0;
                *(int4v*)&xbuf[w][cb][lane * 8 + 4] = p1;
            }

            for (int to = 32; to < 64; to += 8)
#pragma unroll
                for (int u = 0; u < 8; ++u) step(tc + to + u);

            block_sync();                      // chunk tc ready for consumers
        }
        h_last[b * HH + lane] = h;
    } else {
        // ---------------- decode consumer (R5 body, unchanged) ----------------
        const int w = wid - 2;
        const int b = blockIdx.x * 2 + w;

        // lane role: o = lane>>2 (output col, valid < 11), ks = lane&3
        // (K-slice: h pairs 8ks..8ks+7). wdec[p] = (W_dec[o][2(8ks+p)], ..+1)
        const int od = lane >> 2;
        const int oc = (od < OO) ? od : 0;     // clamp for safe weight loads
        const int ks = lane & 3;
        half2v wdec[8];
#pragma unroll
        for (int p = 0; p < 8; ++p)
            wdec[p] = __builtin_amdgcn_cvt_pkrtz(
                W_dec[oc * HH + (ks * 8 + p) * 2],
                W_dec[oc * HH + (ks * 8 + p) * 2 + 1]);
        const float bd = b_dec[oc];
        const bool dostore = (ks == 0) && (od < OO);
        float* outb = out + (size_t)b * TT * OO + od;

        for (int c = 0; c < TT / 64; ++c) {
            block_sync();                      // wait for producer chunk c
#pragma unroll 4
            for (int lt = 0; lt < 64; ++lt) {
                const int t = c * 64 + lt;
                const char* row = (const char*)&hring[w][t & 127][0];
                const int4v d0 = *(const int4v*)(row + ks * 32);
                const int4v d1 = *(const int4v*)(row + ks * 32 + 16);
                float dacc = FDOT2(i2h2(d0.x), wdec[0], 0.0f);
                dacc = FDOT2(i2h2(d0.y), wdec[1], dacc);
                dacc = FDOT2(i2h2(d0.z), wdec[2], dacc);
                dacc = FDOT2(i2h2(d0.w), wdec[3], dacc);
                dacc = FDOT2(i2h2(d1.x), wdec[4], dacc);
                dacc = FDOT2(i2h2(d1.y), wdec[5], dacc);
                dacc = FDOT2(i2h2(d1.z), wdec[6], dacc);
                dacc = FDOT2(i2h2(d1.w), wdec[7], dacc);
                dacc += lane_xor1(dacc);       // quad reduce over ks
                dacc += lane_xor2(dacc);
                if (dostore)
                    outb[(size_t)t * OO] = fmaxf(dacc + bd, 0.0f);
            }
        }
    }
}

extern "C" void kernel_launch(void* const* d_in, const int* in_sizes, int n_in,
                              void* d_out, int out_size, void* d_ws, size_t ws_size,
                              hipStream_t stream) {
    const float* x     = (const float*)d_in[0];
    const float* W_ih  = (const float*)d_in[1];
    const float* b_ih  = (const float*)d_in[2];
    const float* W_hh  = (const float*)d_in[3];
    const float* b_hh  = (const float*)d_in[4];
    const float* W_dec = (const float*)d_in[5];
    const float* b_dec = (const float*)d_in[6];

    float* out    = (float*)d_out;
    float* h_last = out + (size_t)BB * TT * OO;   // second tuple output

    rnn_fused<<<BB / 2, 256, 0, stream>>>(x, W_ih, b_ih, W_hh, b_hh,
                                          W_dec, b_dec, out, h_last);
}

// Round 7
// 246.659 us; speedup vs baseline: 1.0919x; 1.0919x over previous
//
#include <hip/hip_runtime.h>
#include <hip/hip_fp16.h>
#include <stdint.h>

#define BB 512
#define TT 1024
#define II 15
#define HH 64
#define OO 11
#define NC (TT / 64)

typedef __fp16 half2v __attribute__((ext_vector_type(2)));
typedef float floatx4 __attribute__((ext_vector_type(4)));
typedef int int4v __attribute__((ext_vector_type(4)));

union PK { int i; half2v h; float f; };

__device__ __forceinline__ half2v i2h2(int v) { PK u; u.i = v; return u.h; }
__device__ __forceinline__ int h22i(half2v v) { PK u; u.h = v; return u.i; }

__device__ __forceinline__ float FDOT2(half2v a, half2v b, float c) {
    return __builtin_amdgcn_fdot2(a, b, c, false);
}

__device__ __forceinline__ float lane_xor1(float v) {
    PK u; u.f = v;
    // quad_perm(1,0,3,2) = 0xB1 : lane -> lane^1
    u.i = __builtin_amdgcn_mov_dpp(u.i, 0xB1, 0xF, 0xF, false);
    return u.f;
}

__device__ __forceinline__ float lane_xor2(float v) {
    PK u; u.f = v;
    // quad_perm(2,3,0,1) = 0x4E : lane -> lane^2
    u.i = __builtin_amdgcn_mov_dpp(u.i, 0x4E, 0xF, 0xF, false);
    return u.f;
}

// Drain LDS ops, then workgroup barrier (wave-uniform branches; every wave
// executes exactly 1 + NC barriers).
__device__ __forceinline__ void block_sync() {
    asm volatile("s_waitcnt lgkmcnt(0)" ::: "memory");
    __builtin_amdgcn_s_barrier();
}

// v9: R5 structure (best: 192.3us) + xproj OFFLOADED to the consumer waves.
// R6 (MFMA body) regressed (467 cyc/step): matrix-pipe result latency sits on
// the serial chain exactly where the dots were. Empirical law: step ~= 450cyc
// = ~170 issue + ~140 LDS round trip + tails. The removable issue block is
// xproj: its 8 dots + 2 LDS reads + per-chunk global staging now run on the
// consumer waves (measured ~26K cyc/chunk of slack), which write xs[ts][n]
// (f32, exact same summation tree) into a double-buffered LDS plane one chunk
// ahead. The rec wave is now a PURE recurrence: 7 ds_reads + 32 dots + tree +
// fmax + cvt + ring write per step. No global ops except the final h_last.
// Sync: barrier parity as R5 (1 prologue + NC loop barriers per wave); rec
// reads xsbuf[c&1] while consumers fill xsbuf[(c+1)&1]; decode lags 1 chunk.
__global__ __launch_bounds__(256) void rnn_fused(
    const float* __restrict__ x, const float* __restrict__ W_ih,
    const float* __restrict__ b_ih, const float* __restrict__ W_hh,
    const float* __restrict__ b_hh, const float* __restrict__ W_dec,
    const float* __restrict__ b_dec, float* __restrict__ out,
    float* __restrict__ h_last)
{
    __shared__ __align__(16) int xpack[2][64 * 8];          // 4 KiB
    __shared__ __align__(16) float xsbuf[2][2][64 * 64];    // 64 KiB
    __shared__ __align__(16) _Float16 hring[2][128][HH];    // 32 KiB
    const int tid  = threadIdx.x;
    const int lane = tid & 63;
    const int wid  = tid >> 6;
    const int w = wid & 1;
    const int b = blockIdx.x * 2 + w;
    const float* xb = x + (size_t)b * TT * II;

    if (wid < 2) {
        // ---------------- recurrence producer (pure, R5 dot body) ----------------
        // recurrent weights: whh[p] = (W_hh[lane][2p], W_hh[lane][2p+1])
        half2v whh[32];
#pragma unroll
        for (int p = 0; p < 32; ++p)
            whh[p] = __builtin_amdgcn_cvt_pkrtz(W_hh[lane * HH + 2 * p],
                                                W_hh[lane * HH + 2 * p + 1]);

        hring[w][127][lane] = (_Float16)0.0f;    // h(-1) = 0 lives in slot 127

        block_sync();                            // B0: consumers' xs[0] ready

        float h = 0.0f;
        int hpk = 0;   // packed (h[lane&~1], h[lane|1]) from prev step (h=0)

        for (int c = 0; c < NC; ++c) {
            const float* xsp = &xsbuf[w][c & 1][0];
            for (int to = 0; to < 64; to += 8) {
#pragma unroll
                for (int u = 0; u < 8; ++u) {
                    const int ts = to + u;
                    const int t = c * 64 + ts;

                    // LDS broadcast reads of h(t-1)[16..63] + per-lane xs
                    const int4v* hb4 =
                        (const int4v*)&hring[w][(t + 127) & 127][0];
                    int4v hb[6];
#pragma unroll
                    for (int q = 0; q < 6; ++q) hb[q] = hb4[q + 2];
                    const float xsv = xsp[ts * 64 + lane];

                    // register-broadcast path: h(t-1)[0..15] pairs live in
                    // even lanes' hpk; fills the DS round-trip window
                    float a0, a1, a2, a3, a4, a5, a6, a7;
                    a0 = FDOT2(i2h2(__builtin_amdgcn_readlane(hpk, 0)),  whh[0], 0.0f);
                    a1 = FDOT2(i2h2(__builtin_amdgcn_readlane(hpk, 2)),  whh[1], 0.0f);
                    a2 = FDOT2(i2h2(__builtin_amdgcn_readlane(hpk, 4)),  whh[2], 0.0f);
                    a3 = FDOT2(i2h2(__builtin_amdgcn_readlane(hpk, 6)),  whh[3], 0.0f);
                    a4 = FDOT2(i2h2(__builtin_amdgcn_readlane(hpk, 8)),  whh[4], 0.0f);
                    a5 = FDOT2(i2h2(__builtin_amdgcn_readlane(hpk, 10)), whh[5], 0.0f);
                    a6 = FDOT2(i2h2(__builtin_amdgcn_readlane(hpk, 12)), whh[6], 0.0f);
                    a7 = FDOT2(i2h2(__builtin_amdgcn_readlane(hpk, 14)), whh[7], 0.0f);

                    // LDS dots: round q consumes hb[q] (pairs 8+4q .. 11+4q)
#pragma unroll
                    for (int q = 0; q < 6; ++q) {
                        const int base = 8 + 4 * q;
                        if ((q & 1) == 0) {
                            a0 = FDOT2(i2h2(hb[q].x), whh[base + 0], a0);
                            a1 = FDOT2(i2h2(hb[q].y), whh[base + 1], a1);
                            a2 = FDOT2(i2h2(hb[q].z), whh[base + 2], a2);
                            a3 = FDOT2(i2h2(hb[q].w), whh[base + 3], a3);
                        } else {
                            a4 = FDOT2(i2h2(hb[q].x), whh[base + 0], a4);
                            a5 = FDOT2(i2h2(hb[q].y), whh[base + 1], a5);
                            a6 = FDOT2(i2h2(hb[q].z), whh[base + 2], a6);
                            a7 = FDOT2(i2h2(hb[q].w), whh[base + 3], a7);
                        }
                    }
                    const float s = ((a0 + a1) + (a2 + a3)) +
                                    ((a4 + a5) + (a6 + a7));
                    h = fmaxf(s + xsv, 0.0f);
                    hring[w][t & 127][lane] = (_Float16)h;   // publish h(t)

                    // pack pair for next step's readlane path (off the DS pipe)
                    hpk = h22i(__builtin_amdgcn_cvt_pkrtz(h, lane_xor1(h)));
                }
            }
            block_sync();                      // chunk c h ready; xs[c+1] ready
        }
        h_last[b * HH + lane] = h;
    } else {
        // -------- consumer: xproj producer (1 chunk ahead) + decoder (1 behind) --------
        // xproj weights, lane = n: pair 7 = (w14, bias) matching x pair (x14, 1.0)
        half2v wx[8];
#pragma unroll
        for (int j = 0; j < 7; ++j)
            wx[j] = __builtin_amdgcn_cvt_pkrtz(W_ih[lane * II + 2 * j],
                                               W_ih[lane * II + 2 * j + 1]);
        wx[7] = __builtin_amdgcn_cvt_pkrtz(W_ih[lane * II + 14],
                                           b_ih[lane] + b_hh[lane]);

        // decode lane role: o = lane>>2 (output col, valid < 11), ks = lane&3
        const int od = lane >> 2;
        const int oc = (od < OO) ? od : 0;     // clamp for safe weight loads
        const int ks = lane & 3;
        half2v wdec[8];
#pragma unroll
        for (int p = 0; p < 8; ++p)
            wdec[p] = __builtin_amdgcn_cvt_pkrtz(
                W_dec[oc * HH + (ks * 8 + p) * 2],
                W_dec[oc * HH + (ks * 8 + p) * 2 + 1]);
        const float bd = b_dec[oc];
        const bool dostore = (ks == 0) && (od < OO);
        float* outb = out + (size_t)b * TT * OO + od;

        // stage x chunk + compute xs plane for that chunk (lane = ts for
        // staging, lane = n for the dot loop; in-wave LDS RAW is in-order)
        auto stage_xs = [&](int chunk) __attribute__((always_inline)) {
            const float* xc = xb + (size_t)(chunk * 64 + lane) * II;
            float cf[II];
#pragma unroll
            for (int i = 0; i < II; ++i) cf[i] = xc[i];
            int4v p0, p1;
            p0.x = h22i(__builtin_amdgcn_cvt_pkrtz(cf[0], cf[1]));
            p0.y = h22i(__builtin_amdgcn_cvt_pkrtz(cf[2], cf[3]));
            p0.z = h22i(__builtin_amdgcn_cvt_pkrtz(cf[4], cf[5]));
            p0.w = h22i(__builtin_amdgcn_cvt_pkrtz(cf[6], cf[7]));
            p1.x = h22i(__builtin_amdgcn_cvt_pkrtz(cf[8], cf[9]));
            p1.y = h22i(__builtin_amdgcn_cvt_pkrtz(cf[10], cf[11]));
            p1.z = h22i(__builtin_amdgcn_cvt_pkrtz(cf[12], cf[13]));
            p1.w = h22i(__builtin_amdgcn_cvt_pkrtz(cf[14], 1.0f));
            *(int4v*)&xpack[w][lane * 8] = p0;
            *(int4v*)&xpack[w][lane * 8 + 4] = p1;

            const int4v* xp4 = (const int4v*)&xpack[w][0];
            float* xsd = &xsbuf[w][chunk & 1][0];
#pragma unroll 4
            for (int ts = 0; ts < 64; ++ts) {
                const int4v xv0 = xp4[2 * ts];      // uniform-addr broadcast
                const int4v xv1 = xp4[2 * ts + 1];
                float t0 = FDOT2(i2h2(xv0.x), wx[0], 0.0f);
                float t1 = FDOT2(i2h2(xv0.y), wx[1], 0.0f);
                float t2 = FDOT2(i2h2(xv0.z), wx[2], 0.0f);
                float t3 = FDOT2(i2h2(xv0.w), wx[3], 0.0f);
                float t4 = FDOT2(i2h2(xv1.x), wx[4], 0.0f);
                float t5 = FDOT2(i2h2(xv1.y), wx[5], 0.0f);
                float t6 = FDOT2(i2h2(xv1.z), wx[6], 0.0f);
                float t7 = FDOT2(i2h2(xv1.w), wx[7], 0.0f);
                xsd[ts * 64 + lane] = ((t0 + t1) + (t2 + t3)) +
                                      ((t4 + t5) + (t6 + t7));
            }
        };

        auto decode_chunk = [&](int c) __attribute__((always_inline)) {
#pragma unroll 4
            for (int lt = 0; lt < 64; ++lt) {
                const int t = c * 64 + lt;
                const char* row = (const char*)&hring[w][t & 127][0];
                const int4v d0 = *(const int4v*)(row + ks * 32);
                const int4v d1 = *(const int4v*)(row + ks * 32 + 16);
                float dacc = FDOT2(i2h2(d0.x), wdec[0], 0.0f);
                dacc = FDOT2(i2h2(d0.y), wdec[1], dacc);
                dacc = FDOT2(i2h2(d0.z), wdec[2], dacc);
                dacc = FDOT2(i2h2(d0.w), wdec[3], dacc);
                dacc = FDOT2(i2h2(d1.x), wdec[4], dacc);
                dacc = FDOT2(i2h2(d1.y), wdec[5], dacc);
                dacc = FDOT2(i2h2(d1.z), wdec[6], dacc);
                dacc = FDOT2(i2h2(d1.w), wdec[7], dacc);
                dacc += lane_xor1(dacc);       // quad reduce over ks
                dacc += lane_xor2(dacc);
                if (dostore)
                    outb[(size_t)t * OO] = fmaxf(dacc + bd, 0.0f);
            }
        };

        stage_xs(0);
        block_sync();                          // B0

        for (int c = 0; c < NC; ++c) {
            if (c + 1 < NC) stage_xs(c + 1);   // fill xsbuf[(c+1)&1]
            if (c >= 1) decode_chunk(c - 1);   // rec writes the other half
            block_sync();
        }
        decode_chunk(NC - 1);                  // after final barrier; no more syncs
    }
}

extern "C" void kernel_launch(void* const* d_in, const int* in_sizes, int n_in,
                              void* d_out, int out_size, void* d_ws, size_t ws_size,
                              hipStream_t stream) {
    const float* x     = (const float*)d_in[0];
    const float* W_ih  = (const float*)d_in[1];
    const float* b_ih  = (const float*)d_in[2];
    const float* W_hh  = (const float*)d_in[3];
    const float* b_hh  = (const float*)d_in[4];
    const float* W_dec = (const float*)d_in[5];
    const float* b_dec = (const float*)d_in[6];

    float* out    = (float*)d_out;
    float* h_last = out + (size_t)BB * TT * OO;   // second tuple output

    rnn_fused<<<BB / 2, 256, 0, stream>>>(x, W_ih, b_ih, W_hh, b_hh,
                                          W_dec, b_dec, out, h_last);
}